// Round 6
// baseline (149.565 us; speedup 1.0000x reference)
//
#include <hip/hip_runtime.h>

// YOLO loss on MI355X — round 6: round-5 pipeline with the spill fixed.
// Round 5's register-prefetch pipeline spilled rp[15] to scratch
// (__launch_bounds__(64) let the allocator cap VGPRs at 68 -> 91 MB of
// scratch writes, WRITE_SIZE counter). One-line fix: __launch_bounds__(64,2)
// raises the VGPR budget to 256/wave; occupancy stays LDS-capped at 10
// blocks/CU (15360 B each) regardless.
// Structure: persistent 1-wave blocks stride over 64-cell tiles; per tile:
// commit prefetched regs->LDS, issue next tile's 15 float4 loads (fly during
// compute), compute one cell/lane from LDS, accumulate lane loss. One
// partial per block; deterministic two-kernel reduction.

#define TILE 64
#define NBLOCKS 2560   // 10 blocks/CU * 256 CU

__global__ __launch_bounds__(64, 2) void yolo_cell_kernel(
    const float* __restrict__ pred, const float* __restrict__ targ,
    float* __restrict__ block_sums, int n_cells)
{
    __shared__ float4 lds4[TILE * 30 * 2 / 4];  // 960 float4 = 15360 B
    float* lds = reinterpret_cast<float*>(lds4);
    const float* lds_p = lds;                   // floats [0, 1920)
    const float* lds_t = lds + TILE * 30;       // floats [1920, 3840)

    const int t = threadIdx.x;                  // 0..63, one wave
    const int n_tiles = (n_cells + TILE - 1) / TILE;
    const int stride = gridDim.x;

    float lane_loss = 0.0f;
    float4 rp[15];                              // prefetch regs (60 VGPR, no spill)

    int tile = blockIdx.x;
    bool pref = false;
    if (tile < n_tiles && (tile + 1) * TILE <= n_cells) {
        const float4* gp = reinterpret_cast<const float4*>(pred + (size_t)tile * TILE * 30);
        const float4* gt = reinterpret_cast<const float4*>(targ + (size_t)tile * TILE * 30);
#pragma unroll
        for (int i = 0; i < 15; ++i) {
            int k = i * 64 + t;                 // 0..959: <480 pred, else targ
            rp[i] = (k < 480) ? gp[k] : gt[k - 480];
        }
        pref = true;
    }

    for (; tile < n_tiles; tile += stride) {
        const int tile_cells = min(TILE, n_cells - tile * TILE);

        if (pref) {
            // commit this tile's regs to LDS (compiler inserts vmcnt wait)
#pragma unroll
            for (int i = 0; i < 15; ++i)
                lds4[i * 64 + t] = rp[i];
            // prefetch next full tile into the same regs (expcnt-guarded WAR);
            // these loads fly while we compute the current tile below.
            int next = tile + stride;
            if (next < n_tiles && (next + 1) * TILE <= n_cells) {
                const float4* gp = reinterpret_cast<const float4*>(pred + (size_t)next * TILE * 30);
                const float4* gt = reinterpret_cast<const float4*>(targ + (size_t)next * TILE * 30);
#pragma unroll
                for (int i = 0; i < 15; ++i) {
                    int k = i * 64 + t;
                    rp[i] = (k < 480) ? gp[k] : gt[k - 480];
                }
                pref = true;
            } else {
                pref = false;
            }
        } else {
            // partial tile (only ever the globally-last tile): scalar staging
            int nf = tile_cells * 30;
            const float* gp = pred + (size_t)tile * TILE * 30;
            const float* gt = targ + (size_t)tile * TILE * 30;
            for (int i = t; i < nf; i += 64) {
                lds[i] = gp[i];
                lds[TILE * 30 + i] = gt[i];
            }
        }

        // order LDS writes before LDS reads WITHOUT draining vmcnt (a
        // __syncthreads here would emit vmcnt(0) and kill the prefetch).
        // gfx9 encoding: vmcnt=63, expcnt=7, lgkmcnt=0 -> 0xC07F.
        __builtin_amdgcn_s_waitcnt(0xC07F);

        if (t < tile_cells) {
            const float* pv = lds_p + t * 30;   // stride-30: 4-way LDS alias,
            const float* tv = lds_t + t * 30;   // tiny traffic, negligible

            float loss;
            float conf_t = tv[4];
            if (conf_t == 0.0f) {
                float d4 = pv[4] - tv[4];
                float d9 = pv[9] - tv[9];
                loss = 0.5f * (d4 * d4 + d9 * d9);
            } else {
                float cls = 0.0f;
#pragma unroll
                for (int c = 10; c < 30; ++c) {
                    float d = pv[c] - tv[c];
                    cls += d * d;
                }

                // target box 0 -> xyxy (mirror reference arithmetic exactly)
                float t0x = tv[0] / 14.0f, t0y = tv[1] / 14.0f;
                float tx1 = t0x - 0.5f * tv[2], ty1 = t0y - 0.5f * tv[3];
                float tx2 = t0x + 0.5f * tv[2], ty2 = t0y + 0.5f * tv[3];
                float area_t = (tx2 - tx1) * (ty2 - ty1);

                float iou0, iou1;
#pragma unroll
                for (int b = 0; b < 2; ++b) {
                    float bx = pv[5*b + 0] / 14.0f, by = pv[5*b + 1] / 14.0f;
                    float px1 = bx - 0.5f * pv[5*b + 2], py1 = by - 0.5f * pv[5*b + 3];
                    float px2 = bx + 0.5f * pv[5*b + 2], py2 = by + 0.5f * pv[5*b + 3];
                    float ltx = fmaxf(px1, tx1), lty = fmaxf(py1, ty1);
                    float rbx = fminf(px2, tx2), rby = fminf(py2, ty2);
                    float iw = fmaxf(rbx - ltx, 0.0f), ih = fmaxf(rby - lty, 0.0f);
                    float inter = iw * ih;
                    float area_p = (px2 - px1) * (py2 - py1);
                    float v = inter / (area_p + area_t - inter);
                    if (b == 0) iou0 = v; else iou1 = v;
                }

                bool sel1 = iou1 > iou0;        // tie -> box 0 (argmax semantics)
                float max_iou = sel1 ? iou1 : iou0;

                float ps0 = sel1 ? pv[5] : pv[0];
                float ps1 = sel1 ? pv[6] : pv[1];
                float ps2 = sel1 ? pv[7] : pv[2];
                float ps3 = sel1 ? pv[8] : pv[3];
                float ps4 = sel1 ? pv[9] : pv[4];
                float ts0 = sel1 ? tv[5] : tv[0];
                float ts1 = sel1 ? tv[6] : tv[1];
                float ts2 = sel1 ? tv[7] : tv[2];
                float ts3 = sel1 ? tv[8] : tv[3];
                float notresp_conf = sel1 ? pv[4] : pv[9];

                float dconf = ps4 - max_iou;
                float dx = ps0 - ts0, dy = ps1 - ts1;
                float dw = sqrtf(ps2) - sqrtf(ts2);
                float dh = sqrtf(ps3) - sqrtf(ts3);
                float loc = dx * dx + dy * dy + dw * dw + dh * dh;

                loss = 5.0f * loc + 2.0f * dconf * dconf
                     + notresp_conf * notresp_conf + cls;
            }
            lane_loss += loss;   // fixed tile order per lane: deterministic
        }
        // single wave: lockstep; next iteration's ds_writes can't pass the
        // in-order LDS pipe ahead of this iteration's reads
    }

    // one wave reduction at the end; lane 0 writes the block partial
#pragma unroll
    for (int off = 32; off > 0; off >>= 1)
        lane_loss += __shfl_down(lane_loss, off, 64);
    if (t == 0)
        block_sums[blockIdx.x] = lane_loss;
}

__global__ __launch_bounds__(1024) void yolo_reduce_kernel(
    const float* __restrict__ block_sums, int n, double inv_batch,
    float* __restrict__ out)
{
    double acc = 0.0;
    for (int i = threadIdx.x; i < n; i += 1024)
        acc += (double)block_sums[i];
#pragma unroll
    for (int off = 32; off > 0; off >>= 1)
        acc += __shfl_down(acc, off, 64);

    __shared__ double wsum[16];
    int lane = threadIdx.x & 63;
    int wid  = threadIdx.x >> 6;
    if (lane == 0) wsum[wid] = acc;
    __syncthreads();
    if (threadIdx.x == 0) {
        double s = 0.0;
#pragma unroll
        for (int w = 0; w < 16; ++w) s += wsum[w];
        out[0] = (float)(s * inv_batch);
    }
}

extern "C" void kernel_launch(void* const* d_in, const int* in_sizes, int n_in,
                              void* d_out, int out_size, void* d_ws, size_t ws_size,
                              hipStream_t stream) {
    const float* pred = (const float*)d_in[0];
    const float* targ = (const float*)d_in[1];
    float* out = (float*)d_out;
    float* block_sums = (float*)d_ws;  // fully written before read; poison ok

    int n_elems  = in_sizes[0];         // B*14*14*30
    int n_cells  = n_elems / 30;        // B*196
    int n_batch  = n_cells / (14 * 14); // B
    int n_tiles  = (n_cells + TILE - 1) / TILE;   // 6272 for B=2048
    int n_blocks = n_tiles < NBLOCKS ? n_tiles : NBLOCKS;

    yolo_cell_kernel<<<n_blocks, TILE, 0, stream>>>(pred, targ, block_sums, n_cells);
    yolo_reduce_kernel<<<1, 1024, 0, stream>>>(block_sums, n_blocks,
                                               1.0 / (double)n_batch, out);
}

// Round 7
// 113.324 us; speedup vs baseline: 1.3198x; 1.3198x over previous
//
#include <hip/hip_runtime.h>

// YOLO loss on MI355X — round 7: revert to round-4 structure (best: 113.8 us).
// Rounds 5/6's register-prefetch pipeline spilled to scratch (VGPR=68,
// WRITE_SIZE=91 MB) and regressed; launch_bounds couldn't fix the allocator.
// Trajectory evidence (R1 29us / R2 27us / R4 26us across three different
// structures) says the cell kernel sits at the irreducible-bytes ceiling:
// 192 MB of read-once input at ~7.4 TB/s effective fabric read BW.
// Structure: one 64-thread (1-wave) block stages a 64-cell tile (15360 B
// fused pred|targ LDS image) with aligned float4 loads, computes one cell
// per thread, wave-reduces, one partial per block. Micro-tweak vs R4:
// __syncthreads() -> s_waitcnt lgkmcnt(0) only (0xC07F) — single-wave
// workgroup needs ds_write->ds_read ordering, not a barrier + vmcnt drain.

#define TILE 64

__global__ __launch_bounds__(64) void yolo_cell_kernel(
    const float* __restrict__ pred, const float* __restrict__ targ,
    float* __restrict__ block_sums, int n_cells)
{
    __shared__ float4 lds4[TILE * 30 * 2 / 4];  // 960 float4 = 15360 B
    float* lds = reinterpret_cast<float*>(lds4);
    const float* lds_p = lds;                   // floats [0, 1920)
    const float* lds_t = lds + TILE * 30;       // floats [1920, 3840)

    const int t = threadIdx.x;                  // 0..63, one wave
    const int cell0 = blockIdx.x * TILE;
    const int tile_cells = min(TILE, n_cells - cell0);

    if (tile_cells == TILE) {
        // full tile: bases 16B-aligned (64*30*4 = 7680 B per tile)
        const float4* gp = reinterpret_cast<const float4*>(pred + (size_t)cell0 * 30);
        const float4* gt = reinterpret_cast<const float4*>(targ + (size_t)cell0 * 30);
#pragma unroll
        for (int i = 0; i < 15; ++i) {
            int k = i * 64 + t;                 // 0..959: <480 pred, else targ
            lds4[k] = (k < 480) ? gp[k] : gt[k - 480];
        }
    } else {
        // generic tail (not taken when n_cells % 64 == 0)
        int nf = tile_cells * 30;
        const float* gp = pred + (size_t)cell0 * 30;
        const float* gt = targ + (size_t)cell0 * 30;
        for (int i = t; i < nf; i += 64) {
            lds[i] = gp[i];
            lds[TILE * 30 + i] = gt[i];
        }
    }
    // single-wave workgroup: only need LDS write->read ordering.
    // gfx9 s_waitcnt encoding: vmcnt=63, expcnt=7, lgkmcnt=0 -> 0xC07F.
    __builtin_amdgcn_s_waitcnt(0xC07F);

    float loss = 0.0f;
    if (t < tile_cells) {
        const float* pv = lds_p + t * 30;   // stride-30 -> 4-way LDS aliasing,
        const float* tv = lds_t + t * 30;   // tiny traffic: negligible

        float conf_t = tv[4];
        if (conf_t == 0.0f) {
            float d4 = pv[4] - tv[4];
            float d9 = pv[9] - tv[9];
            loss = 0.5f * (d4 * d4 + d9 * d9);
        } else {
            float cls = 0.0f;
#pragma unroll
            for (int c = 10; c < 30; ++c) {
                float d = pv[c] - tv[c];
                cls += d * d;
            }

            // target box 0 -> xyxy (mirror reference arithmetic exactly)
            float t0x = tv[0] / 14.0f, t0y = tv[1] / 14.0f;
            float tx1 = t0x - 0.5f * tv[2], ty1 = t0y - 0.5f * tv[3];
            float tx2 = t0x + 0.5f * tv[2], ty2 = t0y + 0.5f * tv[3];
            float area_t = (tx2 - tx1) * (ty2 - ty1);

            float iou0, iou1;
#pragma unroll
            for (int b = 0; b < 2; ++b) {
                float bx = pv[5*b + 0] / 14.0f, by = pv[5*b + 1] / 14.0f;
                float px1 = bx - 0.5f * pv[5*b + 2], py1 = by - 0.5f * pv[5*b + 3];
                float px2 = bx + 0.5f * pv[5*b + 2], py2 = by + 0.5f * pv[5*b + 3];
                float ltx = fmaxf(px1, tx1), lty = fmaxf(py1, ty1);
                float rbx = fminf(px2, tx2), rby = fminf(py2, ty2);
                float iw = fmaxf(rbx - ltx, 0.0f), ih = fmaxf(rby - lty, 0.0f);
                float inter = iw * ih;
                float area_p = (px2 - px1) * (py2 - py1);
                float v = inter / (area_p + area_t - inter);
                if (b == 0) iou0 = v; else iou1 = v;
            }

            bool sel1 = iou1 > iou0;          // tie -> box 0 (argmax semantics)
            float max_iou = sel1 ? iou1 : iou0;

            float ps0 = sel1 ? pv[5] : pv[0];
            float ps1 = sel1 ? pv[6] : pv[1];
            float ps2 = sel1 ? pv[7] : pv[2];
            float ps3 = sel1 ? pv[8] : pv[3];
            float ps4 = sel1 ? pv[9] : pv[4];
            float ts0 = sel1 ? tv[5] : tv[0];
            float ts1 = sel1 ? tv[6] : tv[1];
            float ts2 = sel1 ? tv[7] : tv[2];
            float ts3 = sel1 ? tv[8] : tv[3];
            float notresp_conf = sel1 ? pv[4] : pv[9];

            float dconf = ps4 - max_iou;
            float dx = ps0 - ts0, dy = ps1 - ts1;
            float dw = sqrtf(ps2) - sqrtf(ts2);
            float dh = sqrtf(ps3) - sqrtf(ts3);
            float loc = dx * dx + dy * dy + dw * dw + dh * dh;

            loss = 5.0f * loc + 2.0f * dconf * dconf
                 + notresp_conf * notresp_conf + cls;
        }
    }

    // wave (64-lane) shuffle reduction; lane 0 writes the block partial
#pragma unroll
    for (int off = 32; off > 0; off >>= 1)
        loss += __shfl_down(loss, off, 64);
    if (t == 0)
        block_sums[blockIdx.x] = loss;
}

__global__ __launch_bounds__(1024) void yolo_reduce_kernel(
    const float* __restrict__ block_sums, int n, double inv_batch,
    float* __restrict__ out)
{
    double acc = 0.0;
    for (int i = threadIdx.x; i < n; i += 1024)
        acc += (double)block_sums[i];
#pragma unroll
    for (int off = 32; off > 0; off >>= 1)
        acc += __shfl_down(acc, off, 64);

    __shared__ double wsum[16];
    int lane = threadIdx.x & 63;
    int wid  = threadIdx.x >> 6;
    if (lane == 0) wsum[wid] = acc;
    __syncthreads();
    if (threadIdx.x == 0) {
        double s = 0.0;
#pragma unroll
        for (int w = 0; w < 16; ++w) s += wsum[w];
        out[0] = (float)(s * inv_batch);
    }
}

extern "C" void kernel_launch(void* const* d_in, const int* in_sizes, int n_in,
                              void* d_out, int out_size, void* d_ws, size_t ws_size,
                              hipStream_t stream) {
    const float* pred = (const float*)d_in[0];
    const float* targ = (const float*)d_in[1];
    float* out = (float*)d_out;
    float* block_sums = (float*)d_ws;  // fully written before read; poison ok

    int n_elems  = in_sizes[0];         // B*14*14*30
    int n_cells  = n_elems / 30;        // B*196
    int n_batch  = n_cells / (14 * 14); // B
    int n_blocks = (n_cells + TILE - 1) / TILE;   // 6272 for B=2048

    yolo_cell_kernel<<<n_blocks, TILE, 0, stream>>>(pred, targ, block_sums, n_cells);
    yolo_reduce_kernel<<<1, 1024, 0, stream>>>(block_sums, n_blocks,
                                               1.0 / (double)n_batch, out);
}